// Round 3
// baseline (6402.564 us; speedup 1.0000x reference)
//
#include <hip/hip_runtime.h>
#include <hip/hip_bf16.h>

// Problem constants
#define B_ 4
#define S_ 2048
#define C_ 1024
#define H_ 16
#define HS_ 64
#define M_ 3
#define BS_ (B_ * S_)      // 8192

// ---------------- helpers ----------------
__device__ __forceinline__ void fma4(float4& o, float s, const float4& v) {
    o.x = fmaf(s, v.x, o.x);
    o.y = fmaf(s, v.y, o.y);
    o.z = fmaf(s, v.z, o.z);
    o.w = fmaf(s, v.w, o.w);
}

// ---------------- weight reorders ----------------
// Wq (H,C,HS) -> Wt (C, H*HS)
__global__ __launch_bounds__(256) void reorder_wq(const float* __restrict__ Wq,
                                                  float* __restrict__ Wt) {
    int idx = blockIdx.x * 256 + threadIdx.x;      // C*H*HS = 1M
    int n = idx & 1023;
    int c = idx >> 10;
    int h = n >> 6;
    int d = n & 63;
    Wt[idx] = Wq[((h << 10) + c) * 64 + d];
}

// Wkv[m] (H,C,2HS) -> Wt (C, H*2HS)
__global__ __launch_bounds__(256) void reorder_wkv(const float* __restrict__ Wkv,
                                                   float* __restrict__ Wt) {
    int idx = blockIdx.x * 256 + threadIdx.x;      // C*H*128 = 2M
    int n = idx & 2047;
    int c = idx >> 11;
    int h = n >> 7;
    int d = n & 127;
    Wt[idx] = Wkv[((h << 10) + c) * 128 + d];
}

// ---------------- fp32 GEMM: C = A(M x K) @ B(K x N) (+bias)(+tanh) ----------------
// BM=BN=128, BK=16, 256 threads, 8x8 microtile.
// As padded to 132 words/row: k-stride ≡ 4 (mod 32) -> staging writes are 2-way (free)
template <int ACT>
__global__ __launch_bounds__(256) void gemm_kernel(const float* __restrict__ A,
                                                   const float* __restrict__ Bw,
                                                   const float* __restrict__ bias,
                                                   float* __restrict__ Co,
                                                   int Mr, int Nc, int Kd) {
    __shared__ float As[16][132];   // transposed: As[k][row], padded
    __shared__ float Bs[16][128];   // Bs[k][col]

    const int bn = blockIdx.x * 128;
    const int bm = blockIdx.y * 128;
    const int t  = threadIdx.x;
    const int tx = t & 15;
    const int ty = t >> 4;

    float acc[8][8];
#pragma unroll
    for (int i = 0; i < 8; ++i)
#pragma unroll
        for (int j = 0; j < 8; ++j) acc[i][j] = 0.f;

    for (int k0 = 0; k0 < Kd; k0 += 16) {
        // load A tile 128x16 (512 float4)
#pragma unroll
        for (int rr = 0; rr < 2; ++rr) {
            int idx = t + rr * 256;
            int row = idx >> 2;
            int k4  = (idx & 3) << 2;
            float4 av = *(const float4*)&A[(size_t)(bm + row) * Kd + k0 + k4];
            As[k4 + 0][row] = av.x;
            As[k4 + 1][row] = av.y;
            As[k4 + 2][row] = av.z;
            As[k4 + 3][row] = av.w;
        }
        // load B tile 16x128 (512 float4)
#pragma unroll
        for (int rr = 0; rr < 2; ++rr) {
            int idx = t + rr * 256;
            int kk = idx >> 5;
            int n4 = (idx & 31) << 2;
            *(float4*)&Bs[kk][n4] = *(const float4*)&Bw[(size_t)(k0 + kk) * Nc + bn + n4];
        }
        __syncthreads();

#pragma unroll
        for (int kk = 0; kk < 16; ++kk) {
            float4 a0 = *(float4*)&As[kk][ty * 8];
            float4 a1 = *(float4*)&As[kk][ty * 8 + 4];
            float4 b0 = *(float4*)&Bs[kk][tx * 4];
            float4 b1 = *(float4*)&Bs[kk][64 + tx * 4];
            float a[8] = {a0.x, a0.y, a0.z, a0.w, a1.x, a1.y, a1.z, a1.w};
            float bv[8] = {b0.x, b0.y, b0.z, b0.w, b1.x, b1.y, b1.z, b1.w};
#pragma unroll
            for (int i = 0; i < 8; ++i)
#pragma unroll
                for (int j = 0; j < 8; ++j) acc[i][j] = fmaf(a[i], bv[j], acc[i][j]);
        }
        __syncthreads();
    }

    // epilogue
#pragma unroll
    for (int i = 0; i < 8; ++i) {
        int row = bm + ty * 8 + i;
#pragma unroll
        for (int half = 0; half < 2; ++half) {
            int col = bn + half * 64 + tx * 4;
            float4 r;
            r.x = acc[i][half * 4 + 0];
            r.y = acc[i][half * 4 + 1];
            r.z = acc[i][half * 4 + 2];
            r.w = acc[i][half * 4 + 3];
            if (bias != nullptr) {
                r.x += bias[col + 0];
                r.y += bias[col + 1];
                r.z += bias[col + 2];
                r.w += bias[col + 3];
            }
            if (ACT == 1) {
                r.x = tanhf(r.x); r.y = tanhf(r.y); r.z = tanhf(r.z); r.w = tanhf(r.w);
            }
            *(float4*)&Co[(size_t)row * Nc + col] = r;
        }
    }
}

// ---------------- causal flash attention (fp32), per (b,h,qtile), per-m launch ----------------
// q layout: (BS, H*HS) row b*S+s, col h*64+d
// kv layout: (BS, H*2*HS) row b*S+s, col h*128 + d (k) / h*128+64+d (v)
// out layout: (BS, H*HS) accumulate over m
// LDS: 3 arrays x 64 x 68 x 4B = 52.2 KB (k_s is reused as the P buffer after QK^T)
#define QT_ 64
#define KT_ 64
#define ST_ 68   // padded LDS stride (words), float4-aligned, lane patterns <=2-way

__global__ __launch_bounds__(256) void attn_kernel(const float* __restrict__ qb,
                                                   const float* __restrict__ kvb,
                                                   float* __restrict__ ob,
                                                   int accumulate) {
    const int qtile = blockIdx.x;
    const int bh = blockIdx.y;
    const int b = bh >> 4;       // / H_
    const int h = bh & 15;       // % H_
    const int q0 = qtile * QT_;
    const int t = threadIdx.x;
    const int tx = t & 15;
    const int ty = t >> 4;

    __shared__ float q_s[QT_][ST_];
    __shared__ float k_s[KT_][ST_];   // doubles as P[qrow][kcol] after scores phase
    __shared__ float v_s[KT_][ST_];

    // load q tile (64 rows x 64 d)
    {
        const int lane16 = t & 15;
        const int rbase = t >> 4;
#pragma unroll
        for (int rr = 0; rr < QT_; rr += 16) {
            int r = rbase + rr;
            const float* src = qb + (size_t)(b * S_ + q0 + r) * (H_ * HS_) + h * HS_ + lane16 * 4;
            *(float4*)&q_s[r][lane16 * 4] = *(const float4*)src;
        }
    }

    float m_prev[4], l_run[4];
    float4 o4[4];
#pragma unroll
    for (int i = 0; i < 4; ++i) {
        m_prev[i] = -1e30f;
        l_run[i] = 0.f;
        o4[i] = make_float4(0.f, 0.f, 0.f, 0.f);
    }

    const int kt_last = q0 / KT_;
    for (int kt = 0; kt <= kt_last; ++kt) {
        __syncthreads();   // prev iteration done reading k_s (as P) / v_s
        // load k and v tiles
        {
            const int lane16 = t & 15;
            const int rbase = t >> 4;
#pragma unroll
            for (int rr = 0; rr < KT_; rr += 16) {
                int r = rbase + rr;
                const float* src = kvb + (size_t)(b * S_ + kt * KT_ + r) * (H_ * 2 * HS_)
                                   + h * 2 * HS_ + lane16 * 4;
                *(float4*)&k_s[r][lane16 * 4] = *(const float4*)src;
                *(float4*)&v_s[r][lane16 * 4] = *(const float4*)(src + HS_);
            }
        }
        __syncthreads();

        // scores: rows ty*4+i, cols tx+16*j  (lane-stride = ST_ words -> 2-way max)
        float sc[4][4];
#pragma unroll
        for (int i = 0; i < 4; ++i)
#pragma unroll
            for (int j = 0; j < 4; ++j) sc[i][j] = 0.f;

#pragma unroll
        for (int d = 0; d < HS_; d += 4) {
            float4 qv[4], kv4[4];
#pragma unroll
            for (int i = 0; i < 4; ++i) qv[i] = *(float4*)&q_s[ty * 4 + i][d];
#pragma unroll
            for (int j = 0; j < 4; ++j) kv4[j] = *(float4*)&k_s[tx + 16 * j][d];
#pragma unroll
            for (int i = 0; i < 4; ++i)
#pragma unroll
                for (int j = 0; j < 4; ++j) {
                    sc[i][j] = fmaf(qv[i].x, kv4[j].x, sc[i][j]);
                    sc[i][j] = fmaf(qv[i].y, kv4[j].y, sc[i][j]);
                    sc[i][j] = fmaf(qv[i].z, kv4[j].z, sc[i][j]);
                    sc[i][j] = fmaf(qv[i].w, kv4[j].w, sc[i][j]);
                }
        }

        const float scale = 0.125f;  // HS^-0.5
#pragma unroll
        for (int i = 0; i < 4; ++i)
#pragma unroll
            for (int j = 0; j < 4; ++j) sc[i][j] *= scale;

        if (kt == kt_last) {
#pragma unroll
            for (int i = 0; i < 4; ++i) {
                int rg = q0 + ty * 4 + i;
#pragma unroll
                for (int j = 0; j < 4; ++j) {
                    int cg = kt * KT_ + tx + 16 * j;
                    if (cg > rg) sc[i][j] = -1e30f;
                }
            }
        }

        // online softmax per row (reduce across the 16 tx lanes) — registers only
#pragma unroll
        for (int i = 0; i < 4; ++i) {
            float mrow = fmaxf(fmaxf(sc[i][0], sc[i][1]), fmaxf(sc[i][2], sc[i][3]));
#pragma unroll
            for (int off = 1; off < 16; off <<= 1)
                mrow = fmaxf(mrow, __shfl_xor(mrow, off));
            float mnew = fmaxf(m_prev[i], mrow);
            float corr = __expf(m_prev[i] - mnew);
            float psum = 0.f;
#pragma unroll
            for (int j = 0; j < 4; ++j) {
                float p = __expf(sc[i][j] - mnew);
                sc[i][j] = p;
                psum += p;
            }
#pragma unroll
            for (int off = 1; off < 16; off <<= 1)
                psum += __shfl_xor(psum, off);
            l_run[i] = l_run[i] * corr + psum;
            m_prev[i] = mnew;
            o4[i].x *= corr; o4[i].y *= corr; o4[i].z *= corr; o4[i].w *= corr;
        }

        __syncthreads();   // everyone done READING k_s -> safe to overwrite with P

        // store P into k_s (reused)
#pragma unroll
        for (int i = 0; i < 4; ++i)
#pragma unroll
            for (int j = 0; j < 4; ++j) k_s[ty * 4 + i][tx + 16 * j] = sc[i][j];

        __syncthreads();   // P visible to all

        // PV: o4[i] += P[row][kk] * V[kk][tx*4..], 4 kk at a time
#pragma unroll 4
        for (int kk = 0; kk < KT_; kk += 4) {
            float4 v4[4];
#pragma unroll
            for (int u = 0; u < 4; ++u) v4[u] = *(float4*)&v_s[kk + u][tx * 4];
#pragma unroll
            for (int i = 0; i < 4; ++i) {
                float4 p4 = *(float4*)&k_s[ty * 4 + i][kk];
                fma4(o4[i], p4.x, v4[0]);
                fma4(o4[i], p4.y, v4[1]);
                fma4(o4[i], p4.z, v4[2]);
                fma4(o4[i], p4.w, v4[3]);
            }
        }
    }

    // epilogue: normalize and write/accumulate
#pragma unroll
    for (int i = 0; i < 4; ++i) {
        float inv = 1.f / l_run[i];
        float4 r = o4[i];
        r.x *= inv; r.y *= inv; r.z *= inv; r.w *= inv;
        float* dst = ob + (size_t)(b * S_ + q0 + ty * 4 + i) * (H_ * HS_) + h * HS_ + tx * 4;
        if (accumulate) {
            float4 old = *(float4*)dst;
            r.x += old.x; r.y += old.y; r.z += old.z; r.w += old.w;
        }
        *(float4*)dst = r;
    }
}

// ---------------- launch ----------------
extern "C" void kernel_launch(void* const* d_in, const int* in_sizes, int n_in,
                              void* d_out, int out_size, void* d_ws, size_t ws_size,
                              hipStream_t stream) {
    const float* query_x = (const float*)d_in[0];   // (B,S,C)
    const float* kv_x    = (const float*)d_in[1];   // (M,B,S,C)
    const float* Wq      = (const float*)d_in[2];   // (H,C,HS)
    const float* Wkv     = (const float*)d_in[3];   // (M,H,C,2HS)
    const float* W1      = (const float*)d_in[4];   // (1024,512)
    const float* b1      = (const float*)d_in[5];   // (512)
    const float* W2      = (const float*)d_in[6];   // (512,1024)
    const float* b2      = (const float*)d_in[7];   // (1024)
    float* out = (float*)d_out;                     // (B,S,C)

    float* ws = (float*)d_ws;
    float* wq_t  = ws;                        // 1,048,576
    float* wkv_t = wq_t + 1048576;            // 2,097,152
    float* qb    = wkv_t + 2097152;           // 8,388,608   (BS x 1024)
    float* kvb   = qb + 8388608;              // 16,777,216  (BS x 2048)
    float* attn  = kvb + 16777216;            // 8,388,608   (BS x 1024)
    float* hmid  = attn + 8388608;            // 4,194,304   (BS x 512)

    // 1) reorder Wq, project Q
    reorder_wq<<<4096, 256, 0, stream>>>(Wq, wq_t);
    gemm_kernel<0><<<dim3(1024 / 128, BS_ / 128), 256, 0, stream>>>(
        query_x, wq_t, nullptr, qb, BS_, 1024, 1024);

    // 2) per-source KV projection + attention accumulation
    for (int m = 0; m < M_; ++m) {
        reorder_wkv<<<8192, 256, 0, stream>>>(Wkv + (size_t)m * (H_ * C_ * 2 * HS_), wkv_t);
        gemm_kernel<0><<<dim3(2048 / 128, BS_ / 128), 256, 0, stream>>>(
            kv_x + (size_t)m * (B_ * S_ * C_), wkv_t, nullptr, kvb, BS_, 2048, 1024);
        attn_kernel<<<dim3(S_ / QT_, B_ * H_), 256, 0, stream>>>(qb, kvb, attn, m > 0 ? 1 : 0);
    }

    // 3) MLP: tanh(attn @ W1 + b1) @ W2 + b2
    gemm_kernel<1><<<dim3(512 / 128, BS_ / 128), 256, 0, stream>>>(
        attn, W1, b1, hmid, BS_, 512, 1024);
    gemm_kernel<0><<<dim3(1024 / 128, BS_ / 128), 256, 0, stream>>>(
        hmid, W2, b2, out, BS_, 1024, 512);
}

// Round 9
// 3211.811 us; speedup vs baseline: 1.9934x; 1.9934x over previous
//
#include <hip/hip_runtime.h>
#include <hip/hip_bf16.h>

// Problem constants
#define B_ 4
#define S_ 2048
#define C_ 1024
#define H_ 16
#define HS_ 64
#define M_ 3
#define BS_ (B_ * S_)      // 8192

typedef __attribute__((ext_vector_type(16))) float f32x16;
typedef __attribute__((ext_vector_type(8))) short bf16x8;

// ---------------- helpers ----------------
__device__ __forceinline__ void fma4(float4& o, float s, const float4& v) {
    o.x = fmaf(s, v.x, o.x);
    o.y = fmaf(s, v.y, o.y);
    o.z = fmaf(s, v.z, o.z);
    o.w = fmaf(s, v.w, o.w);
}

__device__ __forceinline__ unsigned cvt_pk_bf16(float lo, float hi) {
    unsigned r;
    asm("v_cvt_pk_bf16_f32 %0, %1, %2" : "=v"(r) : "v"(lo), "v"(hi));
    return r;
}

__device__ __forceinline__ uint4 pk8(const float4& a, const float4& b) {
    uint4 r;
    r.x = cvt_pk_bf16(a.x, a.y);
    r.y = cvt_pk_bf16(a.z, a.w);
    r.z = cvt_pk_bf16(b.x, b.y);
    r.w = cvt_pk_bf16(b.z, b.w);
    return r;
}

__device__ __forceinline__ bf16x8 as_bf16x8(uint4 u) {
    union { uint4 u4; bf16x8 b; } x;
    x.u4 = u;
    return x.b;
}

// D = A(32x16 bf16) * B(16x32 bf16) + C (assumed convention under test).
// D frag: lane l elem r -> D[(r&3)+8*(r>>2)+4*(l>>5)][l&31]   (guide: m74/m101)
__device__ __forceinline__ f32x16 mfma32(uint4 a, uint4 b, f32x16 c) {
    return __builtin_amdgcn_mfma_f32_32x32x16_bf16(as_bf16x8(a), as_bf16x8(b), c, 0, 0, 0);
}

__device__ __forceinline__ uint4 lds_ld16(const unsigned short* base, int byteoff) {
    return *(const uint4*)((const char*)base + byteoff);
}
__device__ __forceinline__ void lds_st16(unsigned short* base, int byteoff, uint4 v) {
    *(uint4*)((char*)base + byteoff) = v;
}

// ---------------- weight reorders ----------------
__global__ __launch_bounds__(256) void reorder_wq(const float* __restrict__ Wq,
                                                  float* __restrict__ Wt) {
    int idx = blockIdx.x * 256 + threadIdx.x;      // C*H*HS = 1M
    int n = idx & 1023;
    int c = idx >> 10;
    int h = n >> 6;
    int d = n & 63;
    Wt[idx] = Wq[((h << 10) + c) * 64 + d];
}

__global__ __launch_bounds__(256) void reorder_wkv(const float* __restrict__ Wkv,
                                                   float* __restrict__ Wt) {
    int idx = blockIdx.x * 256 + threadIdx.x;      // C*H*128 = 2M
    int n = idx & 2047;
    int c = idx >> 11;
    int h = n >> 7;
    int d = n & 127;
    Wt[idx] = Wkv[((h << 10) + c) * 128 + d];
}

// ---------------- fp32 GEMM (known-good from R2 baseline) ----------------
template <int ACT>
__global__ __launch_bounds__(256) void gemm_kernel(const float* __restrict__ A,
                                                   const float* __restrict__ Bw,
                                                   const float* __restrict__ bias,
                                                   float* __restrict__ Co,
                                                   int Mr, int Nc, int Kd) {
    __shared__ float As[16][132];
    __shared__ float Bs[16][128];

    const int bn = blockIdx.x * 128;
    const int bm = blockIdx.y * 128;
    const int t  = threadIdx.x;
    const int tx = t & 15;
    const int ty = t >> 4;

    float acc[8][8];
#pragma unroll
    for (int i = 0; i < 8; ++i)
#pragma unroll
        for (int j = 0; j < 8; ++j) acc[i][j] = 0.f;

    for (int k0 = 0; k0 < Kd; k0 += 16) {
#pragma unroll
        for (int rr = 0; rr < 2; ++rr) {
            int idx = t + rr * 256;
            int row = idx >> 2;
            int k4  = (idx & 3) << 2;
            float4 av = *(const float4*)&A[(size_t)(bm + row) * Kd + k0 + k4];
            As[k4 + 0][row] = av.x;
            As[k4 + 1][row] = av.y;
            As[k4 + 2][row] = av.z;
            As[k4 + 3][row] = av.w;
        }
#pragma unroll
        for (int rr = 0; rr < 2; ++rr) {
            int idx = t + rr * 256;
            int kk = idx >> 5;
            int n4 = (idx & 31) << 2;
            *(float4*)&Bs[kk][n4] = *(const float4*)&Bw[(size_t)(k0 + kk) * Nc + bn + n4];
        }
        __syncthreads();

#pragma unroll
        for (int kk = 0; kk < 16; ++kk) {
            float4 a0 = *(float4*)&As[kk][ty * 8];
            float4 a1 = *(float4*)&As[kk][ty * 8 + 4];
            float4 b0 = *(float4*)&Bs[kk][tx * 4];
            float4 b1 = *(float4*)&Bs[kk][64 + tx * 4];
            float a[8] = {a0.x, a0.y, a0.z, a0.w, a1.x, a1.y, a1.z, a1.w};
            float bv[8] = {b0.x, b0.y, b0.z, b0.w, b1.x, b1.y, b1.z, b1.w};
#pragma unroll
            for (int i = 0; i < 8; ++i)
#pragma unroll
                for (int j = 0; j < 8; ++j) acc[i][j] = fmaf(a[i], bv[j], acc[i][j]);
        }
        __syncthreads();
    }

#pragma unroll
    for (int i = 0; i < 8; ++i) {
        int row = bm + ty * 8 + i;
#pragma unroll
        for (int half = 0; half < 2; ++half) {
            int col = bn + half * 64 + tx * 4;
            float4 r;
            r.x = acc[i][half * 4 + 0];
            r.y = acc[i][half * 4 + 1];
            r.z = acc[i][half * 4 + 2];
            r.w = acc[i][half * 4 + 3];
            if (bias != nullptr) {
                r.x += bias[col + 0];
                r.y += bias[col + 1];
                r.z += bias[col + 2];
                r.w += bias[col + 3];
            }
            if (ACT == 1) {
                r.x = tanhf(r.x); r.y = tanhf(r.y); r.z = tanhf(r.z); r.w = tanhf(r.w);
            }
            *(float4*)&Co[(size_t)row * Nc + col] = r;
        }
    }
}

// ---------------- hybrid attention: MFMA QK^T + fp32 softmax / fp32 VALU PV ----------------
// Block: 256 thr = 4 waves, 128 q rows (wave w owns q = qt*128 + w*32 + l31). KV tile = 64.
// QK^T swapped: s = mfma(K, Q) -> lane owns q-col l31; tokens via D-map.
// P written fp32 to LDS via D-map; PV is the R2-proven fp32 pattern (V staged fp32).
// LDS: k_lds 8KB (bf16 swz) + v_s 17.0KB + p_s 34.0KB + corr_s 0.5KB = 59.5KB
__global__ __launch_bounds__(256) void attn_hybrid(const float* __restrict__ qb,
                                                   const float* __restrict__ kvb,
                                                   float* __restrict__ ob,
                                                   int accumulate) {
    const int qt = blockIdx.x;            // 0..15
    const int bh = blockIdx.y;            // 0..63
    const int b = bh >> 4, head = bh & 15;
    const int tid = threadIdx.x;
    const int lane = tid & 63;
    const int w = tid >> 6;               // wave 0..3
    const int l31 = lane & 31;
    const int h = lane >> 5;              // lane half
    const int qrow = qt * 128 + w * 32 + l31;
    // PV-domain thread indices
    const int tx = tid & 15;              // d-quad
    const int ty = tid >> 4;              // q-group of 8

    __shared__ __align__(16) unsigned short k_lds[64 * 64];  // bf16, XOR-swizzled
    __shared__ float v_s[64][68];                            // V fp32 [tok][d]
    __shared__ float p_s[128][68];                           // P fp32 [q][tok]
    __shared__ float corr_s[128];

    // Q fragment (bf16, x0.125): lane holds Q[qrow][16c + 8h + r]  (B-operand assumption)
    uint4 qf[4];
    {
        const float* qp = qb + ((size_t)(b * S_) + qrow) * 1024 + head * 64;
#pragma unroll
        for (int c = 0; c < 4; ++c) {
            int d0 = 16 * c + 8 * h;
            float4 a = *(const float4*)(qp + d0);
            float4 bv = *(const float4*)(qp + d0 + 4);
            a.x *= 0.125f; a.y *= 0.125f; a.z *= 0.125f; a.w *= 0.125f;
            bv.x *= 0.125f; bv.y *= 0.125f; bv.z *= 0.125f; bv.w *= 0.125f;
            qf[c] = pk8(a, bv);
        }
    }

    float m_prev = -1e30f, l_run = 0.f;
    float4 oacc[8];
#pragma unroll
    for (int i = 0; i < 8; ++i) oacc[i] = make_float4(0.f, 0.f, 0.f, 0.f);

    const int NT = 2 * qt + 2;
    for (int kt = 0; kt < NT; ++kt) {
        __syncthreads();   // prev tile done reading k_lds/v_s/p_s/corr_s
        // ---- stage K (bf16 swizzled) + V (fp32, no transpose) ----
        {
            const int row = tid >> 2;            // 0..63
            const int cs  = (tid & 3) << 4;      // 0,16,32,48
            const int sw  = (row & 7) << 4;
            const int base = row * 128 + cs * 2;
            const float* kp = kvb + ((size_t)(b * S_) + kt * 64 + row) * 2048 + head * 128 + cs;
            float4 a0 = *(const float4*)(kp + 0);
            float4 a1 = *(const float4*)(kp + 4);
            float4 a2 = *(const float4*)(kp + 8);
            float4 a3 = *(const float4*)(kp + 12);
            lds_st16(k_lds, base ^ sw, pk8(a0, a1));
            lds_st16(k_lds, (base + 16) ^ sw, pk8(a2, a3));
            const float* vp = kp + 64;           // V part of same kv row
            *(float4*)&v_s[row][cs + 0]  = *(const float4*)(vp + 0);
            *(float4*)&v_s[row][cs + 4]  = *(const float4*)(vp + 4);
            *(float4*)&v_s[row][cs + 8]  = *(const float4*)(vp + 8);
            *(float4*)&v_s[row][cs + 12] = *(const float4*)(vp + 12);
        }
        __syncthreads();

        // ---- QK^T (swapped): s = mfma(K, Q) ----
        f32x16 s0, s1;
#pragma unroll
        for (int r = 0; r < 16; ++r) { s0[r] = 0.f; s1[r] = 0.f; }
        const int swr = (l31 & 7) << 4;
#pragma unroll
        for (int c = 0; c < 4; ++c) {
            uint4 kf0 = lds_ld16(k_lds, (l31 * 128 + 32 * c + 16 * h) ^ swr);
            uint4 kf1 = lds_ld16(k_lds, ((32 + l31) * 128 + 32 * c + 16 * h) ^ swr);
            s0 = mfma32(kf0, qf[c], s0);
            s1 = mfma32(kf1, qf[c], s1);
        }

        // ---- causal mask + online softmax (registers; lane owns q-row) ----
        float mx = -1e30f;
#pragma unroll
        for (int r = 0; r < 16; ++r) {
            int off = (r & 3) + 8 * (r >> 2) + 4 * h;
            int kc0 = kt * 64 + off;
            int kc1 = kt * 64 + 32 + off;
            float a = (kc0 > qrow) ? -1e30f : s0[r];
            float c2 = (kc1 > qrow) ? -1e30f : s1[r];
            s0[r] = a; s1[r] = c2;
            mx = fmaxf(mx, fmaxf(a, c2));
        }
        mx = fmaxf(mx, __shfl_xor(mx, 32));
        float mnew = fmaxf(m_prev, mx);
        float corr = __expf(m_prev - mnew);
        float ps = 0.f;
#pragma unroll
        for (int r = 0; r < 16; ++r) {
            float p0 = __expf(s0[r] - mnew);
            float p1 = __expf(s1[r] - mnew);
            s0[r] = p0; s1[r] = p1;
            ps += p0 + p1;
        }
        ps += __shfl_xor(ps, 32);
        l_run = l_run * corr + ps;
        m_prev = mnew;
        if (h == 0) corr_s[w * 32 + l31] = corr;
        // ---- write P (fp32) via D-map ----
#pragma unroll
        for (int r = 0; r < 16; ++r) {
            int off = (r & 3) + 8 * (r >> 2) + 4 * h;
            p_s[w * 32 + l31][off] = s0[r];
            p_s[w * 32 + l31][32 + off] = s1[r];
        }
        __syncthreads();

        // ---- fp32 PV (R2-proven pattern): oacc[i] = oacc[i]*corr + sum_k P[q][k]*V[k][d] ----
#pragma unroll
        for (int i = 0; i < 8; ++i) {
            float c = corr_s[ty * 8 + i];
            oacc[i].x *= c; oacc[i].y *= c; oacc[i].z *= c; oacc[i].w *= c;
        }
        for (int kk = 0; kk < 64; kk += 4) {
            float4 v0 = *(float4*)&v_s[kk + 0][tx * 4];
            float4 v1 = *(float4*)&v_s[kk + 1][tx * 4];
            float4 v2 = *(float4*)&v_s[kk + 2][tx * 4];
            float4 v3 = *(float4*)&v_s[kk + 3][tx * 4];
#pragma unroll
            for (int i = 0; i < 8; ++i) {
                float4 p4 = *(float4*)&p_s[ty * 8 + i][kk];
                fma4(oacc[i], p4.x, v0);
                fma4(oacc[i], p4.y, v1);
                fma4(oacc[i], p4.z, v2);
                fma4(oacc[i], p4.w, v3);
            }
        }
    }

    // ---- epilogue ----
    __syncthreads();                        // all PV reads of corr_s done
    if (h == 0) corr_s[w * 32 + l31] = 1.f / l_run;   // reuse as inv-norm
    __syncthreads();
#pragma unroll
    for (int i = 0; i < 8; ++i) {
        const float inv = corr_s[ty * 8 + i];
        float4 r = oacc[i];
        r.x *= inv; r.y *= inv; r.z *= inv; r.w *= inv;
        float* dst = ob + ((size_t)(b * S_) + qt * 128 + ty * 8 + i) * 1024 + head * 64 + tx * 4;
        if (accumulate) {
            float4 old = *(float4*)dst;
            r.x += old.x; r.y += old.y; r.z += old.z; r.w += old.w;
        }
        *(float4*)dst = r;
    }
}

// ---------------- launch ----------------
extern "C" void kernel_launch(void* const* d_in, const int* in_sizes, int n_in,
                              void* d_out, int out_size, void* d_ws, size_t ws_size,
                              hipStream_t stream) {
    const float* query_x = (const float*)d_in[0];
    const float* kv_x    = (const float*)d_in[1];
    const float* Wq      = (const float*)d_in[2];
    const float* Wkv     = (const float*)d_in[3];
    const float* W1      = (const float*)d_in[4];
    const float* b1      = (const float*)d_in[5];
    const float* W2      = (const float*)d_in[6];
    const float* b2      = (const float*)d_in[7];
    float* out = (float*)d_out;

    // regionA (4M floats) multiplexed: wq_t (pre-loop) / wkv_t (per-m) / hmid (post-loop).
    // Peak 37,748,736 floats = 144 MiB (< 156 MiB proven available in R2 run).
    float* ws = (float*)d_ws;
    float* regionA = ws;
    float* wq_t  = regionA;
    float* wkv_t = regionA;
    float* hmid  = regionA;
    float* qb    = ws + 4194304;          // 8M floats
    float* kvb   = ws + 12582912;         // 16M floats
    float* attn  = ws + 29360128;         // 8M floats -> end 37748736

    // 1) Q projection
    reorder_wq<<<4096, 256, 0, stream>>>(Wq, wq_t);
    gemm_kernel<0><<<dim3(1024 / 128, BS_ / 128), 256, 0, stream>>>(
        query_x, wq_t, nullptr, qb, BS_, 1024, 1024);

    // 2) per-source KV projection + hybrid attention
    for (int m = 0; m < M_; ++m) {
        reorder_wkv<<<8192, 256, 0, stream>>>(Wkv + (size_t)m * (H_ * C_ * 2 * HS_), wkv_t);
        gemm_kernel<0><<<dim3(2048 / 128, BS_ / 128), 256, 0, stream>>>(
            kv_x + (size_t)m * (B_ * S_ * C_), wkv_t, nullptr, kvb, BS_, 2048, 1024);
        attn_hybrid<<<dim3(S_ / 128, B_ * H_), 256, 0, stream>>>(qb, kvb, attn, m > 0 ? 1 : 0);
    }

    // 3) MLP
    gemm_kernel<1><<<dim3(512 / 128, BS_ / 128), 256, 0, stream>>>(
        attn, W1, b1, hmid, BS_, 512, 1024);
    gemm_kernel<0><<<dim3(1024 / 128, BS_ / 128), 256, 0, stream>>>(
        hmid, W2, b2, out, BS_, 1024, 512);
}